// Round 7
// baseline (726.135 us; speedup 1.0000x reference)
//
#include <hip/hip_runtime.h>
#include <hip/hip_bf16.h>

#define T_TASKS 8
#define B_ROWS 4096
#define PADROWS 4224      // +128 so partial-tile A loads stay in-bounds
#define BM 128
#define BN 64
#define BK 32
#define MAXTILES 40       // sum over tasks of ceil(cnt/BM) <= T + B/BM = 40

typedef __attribute__((ext_vector_type(4))) float f32x4;
typedef __attribute__((ext_vector_type(8))) short bf16x8;

#define GLOAD_LDS16(g, l) __builtin_amdgcn_global_load_lds( \
    (const __attribute__((address_space(1))) void*)(g), \
    (__attribute__((address_space(3))) void*)(l), 16, 0, 0)

#define WAITV6() asm volatile("s_waitcnt vmcnt(6)" ::: "memory")
#define WAITV3() asm volatile("s_waitcnt vmcnt(3)" ::: "memory")
#define WAITV0() asm volatile("s_waitcnt vmcnt(0)" ::: "memory")
#define BARRIER() do { __builtin_amdgcn_s_barrier(); __builtin_amdgcn_sched_barrier(0); } while (0)

struct TP { const float* src; unsigned short* dst; int K; int N; int ntiles; };

__device__ __forceinline__ unsigned short f32_to_bf16(float f) {
    union { float f; unsigned int u; } v; v.f = f;
    unsigned int r = v.u + 0x7FFF + ((v.u >> 16) & 1);  // RNE
    return (unsigned short)(r >> 16);
}

// ---------------- setup: counting sort by task + tile table ----------------
__global__ void setup_kernel(const int* __restrict__ task, int* __restrict__ perm,
                             int* __restrict__ offs, int* __restrict__ table) {
    __shared__ int cnt[T_TASKS];
    __shared__ int cur[T_TASKS];
    int tid = threadIdx.x;
    if (tid < T_TASKS) cnt[tid] = 0;
    __syncthreads();
    for (int b = tid; b < B_ROWS; b += blockDim.x)
        atomicAdd(&cnt[task[b]], 1);
    __syncthreads();
    if (tid == 0) {
        int o = 0;
        for (int t = 0; t < T_TASKS; ++t) { offs[t] = o; cur[t] = o; o += cnt[t]; }
        offs[T_TASKS] = o;
        int s = 0;
        for (int t = 0; t < T_TASKS; ++t) {
            int nt = (cnt[t] + BM - 1) / BM;
            for (int j = 0; j < nt; ++j) table[s++] = (t << 16) | j;
        }
        for (; s < MAXTILES; ++s) table[s] = -1;
    }
    __syncthreads();
    for (int b = tid; b < B_ROWS; b += blockDim.x) {
        int t = task[b];
        int pos = atomicAdd(&cur[t], 1);
        perm[pos] = b;
    }
}

// ---------------- permute + cast x -> bf16 ----------------
__global__ void permute_cast_kernel(const float* __restrict__ x, const int* __restrict__ perm,
                                    unsigned short* __restrict__ xp) {
    int rowp = blockIdx.x;
    int src = perm[rowp];
    const float4* xin = reinterpret_cast<const float4*>(x + (size_t)src * 1024);
    unsigned short* dst = xp + (size_t)rowp * 1024;
    int c4 = threadIdx.x;
    float4 v = xin[c4];
    ushort4 o;
    o.x = f32_to_bf16(v.x); o.y = f32_to_bf16(v.y);
    o.z = f32_to_bf16(v.z); o.w = f32_to_bf16(v.w);
    *reinterpret_cast<ushort4*>(dst + c4 * 4) = o;
}

// ---------------- VAE reparameterization ----------------
__global__ void vae_kernel(const float* __restrict__ scat, const float* __restrict__ eps,
                           const int* __restrict__ perm, unsigned short* __restrict__ z) {
    int rowp = blockIdx.x;
    int c = threadIdx.x;
    int src = perm[rowp];
    float mu = scat[(size_t)rowp * 512 + c];
    float ls = scat[(size_t)rowp * 512 + 256 + c];
    float e  = eps[(size_t)src * 256 + c];
    z[(size_t)rowp * 256 + c] = f32_to_bf16(mu + __expf(ls) * e);
}

// ---------------- standalone weight transpose (enc_W1 only) ----------------
__global__ __launch_bounds__(256)
void transpose_cast_kernel(const float* __restrict__ W, unsigned short* __restrict__ Wt,
                           int K, int N) {
    const size_t toff = (size_t)blockIdx.z * K * N;
    const float* Ws = W + toff;
    unsigned short* Wd = Wt + toff;
    const int k0 = blockIdx.x * 64;
    const int n0 = blockIdx.y * 64;
    __shared__ unsigned short Tt[64 * 64];
    const int tid = threadIdx.x;
    const int n = tid & 63;
    const int kq = tid >> 6;
    #pragma unroll
    for (int i = 0; i < 4; ++i) {
        int kk = kq * 16 + i * 4;
        const float* p = Ws + (size_t)(k0 + kk) * N + n0 + n;
        float v0 = p[0];
        float v1 = p[(size_t)N];
        float v2 = p[(size_t)2 * N];
        float v3 = p[(size_t)3 * N];
        unsigned int lo = (unsigned int)f32_to_bf16(v0) | ((unsigned int)f32_to_bf16(v1) << 16);
        unsigned int hi = (unsigned int)f32_to_bf16(v2) | ((unsigned int)f32_to_bf16(v3) << 16);
        int c = (kk >> 2) ^ (n & 15);
        *reinterpret_cast<uint2*>(Tt + n * 64 + c * 4) = make_uint2(lo, hi);
    }
    __syncthreads();
    #pragma unroll
    for (int it = 0; it < 2; ++it) {
        int c  = it * 256 + tid;
        int nn = c >> 3;
        int cg = c & 7;
        int c1 = (cg * 2) ^ (nn & 15);
        int c2 = (cg * 2 + 1) ^ (nn & 15);
        uint2 a = *reinterpret_cast<const uint2*>(Tt + nn * 64 + c1 * 4);
        uint2 b = *reinterpret_cast<const uint2*>(Tt + nn * 64 + c2 * 4);
        uint4 o = make_uint4(a.x, a.y, b.x, b.y);
        *reinterpret_cast<uint4*>(Wd + (size_t)(n0 + nn) * K + k0 + cg * 8) = o;
    }
}

// ---------------- fused grouped GEMM (4-buffer counted-vmcnt pipeline) ----------------
// GEMM (bx < GX): A bf16 [rowp][K] grouped; Wt bf16 [t][N][K]; bias f32 [t][N].
//   Both operands via global_load_lds. 4 LDS buffers, 3 K-steps of loads in flight
//   per wave (9 loads). Per step: vmcnt(6) -> s_barrier -> stage(s+3) -> compute(s).
//   vmcnt is NEVER drained to 0 in the main loop (T3+T4). Tail peels vmcnt(3)/vmcnt(0).
//   Swizzle: source chunk ^= ((row>>1)&3) at stage; frag read slot (lane>>4)^((row>>1)&3).
//   XCD-chunked bijective bx remap (GX%8==0, gridDim.x%8==0).
// Transpose (bx >= GX): up to two weight tensors, 64x64 tiles (uses __syncthreads).
// MODE 0: relu -> bf16; MODE 1: f32 store; MODE 2: sigmoid -> f32 scatter via perm
template<int MODE>
__global__ __launch_bounds__(256, 3)
void gemm7_kernel(const unsigned short* __restrict__ A,
                  const unsigned short* __restrict__ Wt,
                  const float* __restrict__ bias, void* __restrict__ dst,
                  const int* __restrict__ offs, const int* __restrict__ table,
                  const int* __restrict__ perm,
                  int K, int N, int ldd, int Btot, int GX, TP tpa, TP tpb)
{
    __shared__ unsigned short As[4][BM * BK];   // 8 KB each
    __shared__ unsigned short Bs[4][BN * BK];   // 4 KB each  (48 KB total)

    const int bxh = blockIdx.x;
    const int tid = threadIdx.x;

    if (bxh >= GX) {
        // ---------- transpose role ----------
        int tile = (bxh - GX) * gridDim.y + blockIdx.y;
        const float* src; unsigned short* dstp; int tK, tN;
        if (tile < tpa.ntiles) { src = tpa.src; dstp = tpa.dst; tK = tpa.K; tN = tpa.N; }
        else {
            tile -= tpa.ntiles;
            if (tile >= tpb.ntiles) return;
            src = tpb.src; dstp = tpb.dst; tK = tpb.K; tN = tpb.N;
        }
        int tk = tK >> 6, tn = tN >> 6;
        int z = tile / (tk * tn);
        int r = tile % (tk * tn);
        int k0 = (r % tk) * 64, n0 = (r / tk) * 64;
        const size_t toff = (size_t)z * tK * tN;
        const float* Ws = src + toff;
        unsigned short* Wd = dstp + toff;
        unsigned short* Tt = &As[0][0];
        const int n = tid & 63;
        const int kq = tid >> 6;
        #pragma unroll
        for (int i = 0; i < 4; ++i) {
            int kk = kq * 16 + i * 4;
            const float* p = Ws + (size_t)(k0 + kk) * tN + n0 + n;
            float v0 = p[0];
            float v1 = p[(size_t)tN];
            float v2 = p[(size_t)2 * tN];
            float v3 = p[(size_t)3 * tN];
            unsigned int lo = (unsigned int)f32_to_bf16(v0) | ((unsigned int)f32_to_bf16(v1) << 16);
            unsigned int hi = (unsigned int)f32_to_bf16(v2) | ((unsigned int)f32_to_bf16(v3) << 16);
            int c = (kk >> 2) ^ (n & 15);
            *reinterpret_cast<uint2*>(Tt + n * 64 + c * 4) = make_uint2(lo, hi);
        }
        __syncthreads();
        #pragma unroll
        for (int it = 0; it < 2; ++it) {
            int c  = it * 256 + tid;
            int nn = c >> 3;
            int cg = c & 7;
            int c1 = (cg * 2) ^ (nn & 15);
            int c2 = (cg * 2 + 1) ^ (nn & 15);
            uint2 a = *reinterpret_cast<const uint2*>(Tt + nn * 64 + c1 * 4);
            uint2 b = *reinterpret_cast<const uint2*>(Tt + nn * 64 + c2 * 4);
            uint4 o = make_uint4(a.x, a.y, b.x, b.y);
            *reinterpret_cast<uint4*>(Wd + (size_t)(n0 + nn) * tK + k0 + cg * 8) = o;
        }
        return;
    }

    // ---------- GEMM role ----------
    int bx = bxh;
    if ((GX & 7) == 0) bx = (bxh & 7) * (GX >> 3) + (bxh >> 3);

    int t, mtile, off, cnt;
    if (table != nullptr) {
        int v = table[bx];
        if (v < 0) return;
        t = v >> 16; mtile = v & 0xFFFF;
        off = offs[t]; cnt = offs[t + 1] - off;
    } else {
        t = 0; mtile = bx; off = 0; cnt = Btot;
    }
    const int n0 = blockIdx.y * BN;

    const int lane = tid & 63;
    const int wave = tid >> 6;
    const int wr = wave >> 1, wc = wave & 1;

    // staging geometry: lane -> row rl=lane>>2 within a 16-row line, chunk lane&3,
    // source chunk XOR ((rl>>1)&3). LDS dest linear.
    const int rl   = lane >> 2;                 // 0..15
    const int csrc = ((lane & 3) ^ ((rl >> 1) & 3)) * 8;
    const unsigned short* Ab = A + ((size_t)(off + mtile * BM + rl)) * K + csrc;
    const unsigned short* Bb = Wt + ((size_t)t * N + n0 + rl) * K + csrc;

    // 3 loads/wave/stage: 2 A-lines + 1 B-line (each 1 KB = 64 lanes x 16 B)
    auto stage = [&](int buf, int k0) {
        #pragma unroll
        for (int jj = 0; jj < 2; ++jj) {
            int j = wave * 2 + jj;              // 0..7: A 16-row line
            GLOAD_LDS16(Ab + (size_t)(j * 16) * K + k0, &As[buf][j * 512]);
        }
        GLOAD_LDS16(Bb + (size_t)(wave * 16) * K + k0, &Bs[buf][wave * 512]);
    };

    f32x4 acc[4][2];
    #pragma unroll
    for (int m = 0; m < 4; ++m)
        #pragma unroll
        for (int n = 0; n < 2; ++n)
            acc[m][n] = (f32x4){0.f, 0.f, 0.f, 0.f};

    auto compute = [&](int buf) {
        bf16x8 af[4], bfr[2];
        #pragma unroll
        for (int m = 0; m < 4; ++m) {
            int rf = wr * 64 + m * 16 + (lane & 15);
            af[m] = *reinterpret_cast<const bf16x8*>(
                &As[buf][rf * 32 + (((lane >> 4) ^ ((rf >> 1) & 3)) * 8)]);
        }
        #pragma unroll
        for (int n = 0; n < 2; ++n) {
            int nf = wc * 32 + n * 16 + (lane & 15);
            bfr[n] = *reinterpret_cast<const bf16x8*>(
                &Bs[buf][nf * 32 + (((lane >> 4) ^ ((nf >> 1) & 3)) * 8)]);
        }
        #pragma unroll
        for (int m = 0; m < 4; ++m)
            #pragma unroll
            for (int n = 0; n < 2; ++n)
                acc[m][n] = __builtin_amdgcn_mfma_f32_16x16x32_bf16(af[m], bfr[n], acc[m][n], 0, 0, 0);
    };

    // ---- 4-buffer, depth-3 pipeline; vmcnt never 0 in main loop ----
    const int nsteps = K / BK;                  // >= 8 for all layers
    stage(0, 0);
    stage(1, BK);
    stage(2, 2 * BK);

    int s = 0;
    for (; s + 3 < nsteps; ++s) {
        WAITV6();                               // oldest 3 (step s) landed
        BARRIER();                              // all waves' step-s writes visible;
                                                // buf[(s-1)&3] fully consumed by all
        stage((s + 3) & 3, (s + 3) * BK);       // refill the just-freed buffer
        compute(s & 3);
    }
    WAITV6(); BARRIER(); compute(s & 3); ++s;   // s = nsteps-3
    WAITV3(); BARRIER(); compute(s & 3); ++s;   // s = nsteps-2
    WAITV0(); BARRIER(); compute(s & 3);        // s = nsteps-1

    // ---- epilogue ----
    const float* bt = bias + (size_t)t * N;
    #pragma unroll
    for (int n = 0; n < 2; ++n) {
        int col = n0 + wc * 32 + n * 16 + (lane & 15);
        float bv = bt[col];
        #pragma unroll
        for (int m = 0; m < 4; ++m) {
            int rbase = mtile * BM + wr * 64 + m * 16 + ((lane >> 4) << 2);
            #pragma unroll
            for (int j = 0; j < 4; ++j) {
                int local = rbase + j;
                if (local >= cnt) continue;
                float v = acc[m][n][j] + bv;
                if (MODE == 0) {
                    ((unsigned short*)dst)[(size_t)(off + local) * ldd + col] =
                        f32_to_bf16(fmaxf(v, 0.f));
                } else if (MODE == 1) {
                    ((float*)dst)[(size_t)(off + local) * ldd + col] = v;
                } else {
                    int grow = perm[off + local];
                    ((float*)dst)[(size_t)grow * ldd + col] = 1.f / (1.f + __expf(-v));
                }
            }
        }
    }
}

extern "C" void kernel_launch(void* const* d_in, const int* in_sizes, int n_in,
                              void* d_out, int out_size, void* d_ws, size_t ws_size,
                              hipStream_t stream) {
    const float* x      = (const float*)d_in[0];
    const int*   task   = (const int*)d_in[1];
    const float* eps    = (const float*)d_in[2];
    const float* enc_W1 = (const float*)d_in[3];
    const float* enc_b1 = (const float*)d_in[4];
    const float* enc_W2 = (const float*)d_in[5];
    const float* enc_b2 = (const float*)d_in[6];
    const float* enc_W3 = (const float*)d_in[7];
    const float* enc_b3 = (const float*)d_in[8];
    const float* enc_W4 = (const float*)d_in[9];
    const float* enc_b4 = (const float*)d_in[10];
    const float* ds_W1  = (const float*)d_in[11];
    const float* ds_b1  = (const float*)d_in[12];
    const float* ds_W2  = (const float*)d_in[13];
    const float* ds_b2  = (const float*)d_in[14];
    const float* hd_W1  = (const float*)d_in[15];
    const float* hd_b1  = (const float*)d_in[16];
    const float* hd_W2  = (const float*)d_in[17];
    const float* hd_b2  = (const float*)d_in[18];
    float* out = (float*)d_out;

    // ---- workspace layout ----
    char* ws = (char*)d_ws;
    int* perm  = (int*)ws;
    int* offs  = (int*)(ws + 16384);
    int* table = (int*)(ws + 16384 + 256);
    char* p = ws + 32768;
    unsigned short* xp = (unsigned short*)p; p += (size_t)PADROWS * 1024 * 2;
    unsigned short* h1 = (unsigned short*)p; p += (size_t)PADROWS * 2048 * 2;
    unsigned short* h2 = (unsigned short*)p; p += (size_t)PADROWS * 2048 * 2;
    unsigned short* zb = (unsigned short*)p; p += (size_t)PADROWS * 256 * 2;
    unsigned short* tw1  = (unsigned short*)p; p += (size_t)8 * 2048 * 1024 * 2;
    unsigned short* tw2  = (unsigned short*)p; p += (size_t)8 * 2048 * 2048 * 2;
    unsigned short* tw3  = (unsigned short*)p; p += (size_t)8 * 2048 * 2048 * 2;
    unsigned short* tw4  = (unsigned short*)p; p += (size_t)8 * 512 * 2048 * 2;
    unsigned short* tds1 = (unsigned short*)p; p += (size_t)2048 * 256 * 2;
    unsigned short* tds2 = (unsigned short*)p; p += (size_t)2048 * 2048 * 2;
    unsigned short* thd1 = (unsigned short*)p; p += (size_t)8 * 2048 * 2048 * 2;
    unsigned short* thd2 = (unsigned short*)p; p += (size_t)8 * 1024 * 2048 * 2;
    float* scat = out;   // reuse d_out as 8 MB scat scratch; fully overwritten later

    const TP tnone = { nullptr, nullptr, 64, 64, 0 };
    const TP tpW2  = { enc_W2, tw2, 2048, 2048, 8192 };
    const TP tpW3  = { enc_W3, tw3, 2048, 2048, 8192 };
    const TP tpW4  = { enc_W4, tw4, 2048,  512, 2048 };
    const TP tpDS1 = { ds_W1, tds1,  256, 2048,  128 };
    const TP tpDS2 = { ds_W2, tds2, 2048, 2048, 1024 };
    const TP tpHD1 = { hd_W1, thd1, 2048, 2048, 8192 };
    const TP tpHD2 = { hd_W2, thd2, 2048, 1024, 4096 };

    setup_kernel<<<1, 1024, 0, stream>>>(task, perm, offs, table);
    permute_cast_kernel<<<B_ROWS, 256, 0, stream>>>(x, perm, xp);

    // enc_W1 must be ready before the first GEMM -> standalone transpose
    transpose_cast_kernel<<<dim3(16, 32, 8), 256, 0, stream>>>(enc_W1, tw1, 1024, 2048);

    // All gridDim.x below are %8==0 so hw xcd == bx%8 for the GEMM remap.
    // D1: enc1 GEMM (GY=32) + transpose enc_W2  (8192/32 = 256 extra -> 296)
    gemm7_kernel<0><<<dim3(296, 32), 256, 0, stream>>>(xp, tw1, enc_b1, h1, offs, table, nullptr, 1024, 2048, 2048, B_ROWS, MAXTILES, tpW2, tnone);
    // D2: enc2 GEMM + transpose enc_W3
    gemm7_kernel<0><<<dim3(296, 32), 256, 0, stream>>>(h1, tw2, enc_b2, h2, offs, table, nullptr, 2048, 2048, 2048, B_ROWS, MAXTILES, tpW3, tnone);
    // D3: enc3 GEMM + transpose enc_W4 + ds_W1  (2176 tiles /32 = 68 -> pad 72 -> 112)
    gemm7_kernel<0><<<dim3(112, 32), 256, 0, stream>>>(h2, tw3, enc_b3, h1, offs, table, nullptr, 2048, 2048, 2048, B_ROWS, MAXTILES, tpW4, tpDS1);
    // D4: enc4 GEMM (GY=8) + transpose ds_W2  (1024/8 = 128 extra -> 168)
    gemm7_kernel<1><<<dim3(168, 8), 256, 0, stream>>>(h1, tw4, enc_b4, scat, offs, table, nullptr, 2048, 512, 512, B_ROWS, MAXTILES, tpDS2, tnone);

    vae_kernel<<<B_ROWS, 256, 0, stream>>>(scat, eps, perm, zb);

    // D5: ds1 GEMM (ungrouped, GX=32, GY=32) + transpose hd_W1  (8192/32 = 256 -> 288)
    gemm7_kernel<0><<<dim3(288, 32), 256, 0, stream>>>(zb, tds1, ds_b1, h2, nullptr, nullptr, nullptr, 256, 2048, 2048, B_ROWS, 32, tpHD1, tnone);
    // D6: ds2 GEMM (ungrouped) + transpose hd_W2  (4096/32 = 128 -> 160)
    gemm7_kernel<0><<<dim3(160, 32), 256, 0, stream>>>(h2, tds2, ds_b2, h1, nullptr, nullptr, nullptr, 2048, 2048, 2048, B_ROWS, 32, tpHD2, tnone);

    // D7: hd1 GEMM (grouped, pure)
    gemm7_kernel<0><<<dim3(MAXTILES, 32), 256, 0, stream>>>(h1, thd1, hd_b1, h2, offs, table, nullptr, 2048, 2048, 2048, B_ROWS, MAXTILES, tnone, tnone);
    // D8: hd2 GEMM (grouped, sigmoid scatter, GY=16)
    gemm7_kernel<2><<<dim3(MAXTILES, 16), 256, 0, stream>>>(h2, thd2, hd_b2, out, offs, table, perm, 2048, 1024, 1024, B_ROWS, MAXTILES, tnone, tnone);
}

// Round 8
// 664.608 us; speedup vs baseline: 1.0926x; 1.0926x over previous
//
#include <hip/hip_runtime.h>
#include <hip/hip_bf16.h>

#define T_TASKS 8
#define B_ROWS 4096
#define PADROWS 4224      // +128 so partial-tile A loads stay in-bounds
#define BM 128
#define BN 64
#define BK 32
#define MAXTILES 40       // sum over tasks of ceil(cnt/BM) <= T + B/BM = 40

typedef __attribute__((ext_vector_type(4))) float f32x4;
typedef __attribute__((ext_vector_type(8))) short bf16x8;

#define GLOAD_LDS16(g, l) __builtin_amdgcn_global_load_lds( \
    (const __attribute__((address_space(1))) void*)(g), \
    (__attribute__((address_space(3))) void*)(l), 16, 0, 0)

__device__ __forceinline__ unsigned short f32_to_bf16(float f) {
    union { float f; unsigned int u; } v; v.f = f;
    unsigned int r = v.u + 0x7FFF + ((v.u >> 16) & 1);  // RNE
    return (unsigned short)(r >> 16);
}

__device__ __forceinline__ unsigned int pack2_bf16(float lo, float hi) {
    __hip_bfloat162 h = __float22bfloat162_rn(make_float2(lo, hi));  // lo -> low 16 bits
    union { __hip_bfloat162 h; unsigned int u; } c; c.h = h;
    return c.u;
}

// ---------------- setup: counting sort by task + tile table ----------------
__global__ void setup_kernel(const int* __restrict__ task, int* __restrict__ perm,
                             int* __restrict__ offs, int* __restrict__ table) {
    __shared__ int cnt[T_TASKS];
    __shared__ int cur[T_TASKS];
    int tid = threadIdx.x;
    if (tid < T_TASKS) cnt[tid] = 0;
    __syncthreads();
    for (int b = tid; b < B_ROWS; b += blockDim.x)
        atomicAdd(&cnt[task[b]], 1);
    __syncthreads();
    if (tid == 0) {
        int o = 0;
        for (int t = 0; t < T_TASKS; ++t) { offs[t] = o; cur[t] = o; o += cnt[t]; }
        offs[T_TASKS] = o;
        int s = 0;
        for (int t = 0; t < T_TASKS; ++t) {
            int nt = (cnt[t] + BM - 1) / BM;
            for (int j = 0; j < nt; ++j) table[s++] = (t << 16) | j;
        }
        for (; s < MAXTILES; ++s) table[s] = -1;
    }
    __syncthreads();
    for (int b = tid; b < B_ROWS; b += blockDim.x) {
        int t = task[b];
        int pos = atomicAdd(&cur[t], 1);
        perm[pos] = b;
    }
}

// ---------------- permute + cast x -> bf16 ----------------
__global__ void permute_cast_kernel(const float* __restrict__ x, const int* __restrict__ perm,
                                    unsigned short* __restrict__ xp) {
    int rowp = blockIdx.x;
    int src = perm[rowp];
    const float4* xin = reinterpret_cast<const float4*>(x + (size_t)src * 1024);
    unsigned short* dst = xp + (size_t)rowp * 1024;
    int c4 = threadIdx.x;
    float4 v = xin[c4];
    ushort4 o;
    o.x = f32_to_bf16(v.x); o.y = f32_to_bf16(v.y);
    o.z = f32_to_bf16(v.z); o.w = f32_to_bf16(v.w);
    *reinterpret_cast<ushort4*>(dst + c4 * 4) = o;
}

// ---------------- VAE reparameterization ----------------
__global__ void vae_kernel(const float* __restrict__ scat, const float* __restrict__ eps,
                           const int* __restrict__ perm, unsigned short* __restrict__ z) {
    int rowp = blockIdx.x;
    int c = threadIdx.x;
    int src = perm[rowp];
    float mu = scat[(size_t)rowp * 512 + c];
    float ls = scat[(size_t)rowp * 512 + 256 + c];
    float e  = eps[(size_t)src * 256 + c];
    z[(size_t)rowp * 256 + c] = f32_to_bf16(mu + __expf(ls) * e);
}

// ---------------- grouped GEMM, f32 [K][N] weights consumed directly ----------------
// A: bf16 [rowp][K] grouped by task (padded rows), staged via global_load_lds
//    (source chunk XOR ((row>>1)&3), linear LDS dest) - R6-proven.
// B: f32 [t][K][N] read IN-KERNEL: each lane does 8 k-strided dword loads at fixed n
//    (per fixed k the wave's 64 lanes span 64 consecutive n -> coalesced 256B),
//    cvt_pk -> one ds_write_b128 into Bs[n][k] at slot c^((n>>1)&3) (conflict-free:
//    groups (4n+slot)&7 cover all 8 per 8 rows) - matches the R6 read swizzle.
// BM=128, BN=64, BK=32, double-buffered 24 KB LDS, 4 waves, XCD-chunked bx remap.
// Pipeline: load_b(s+1) -> stage_a(s+1) -> compute(s) -> write_b(s+1) -> barrier.
// MODE 0: relu -> bf16 store; MODE 1: f32 store; MODE 2: sigmoid -> f32 scatter via perm
template<int MODE>
__global__ __launch_bounds__(256, 4)
void gemm8_kernel(const unsigned short* __restrict__ A,
                  const float* __restrict__ W,
                  const float* __restrict__ bias, void* __restrict__ dst,
                  const int* __restrict__ offs, const int* __restrict__ table,
                  const int* __restrict__ perm,
                  int K, int N, int ldd, int Btot, int GX)
{
    __shared__ unsigned short As[2][BM * BK];   // 8 KB each
    __shared__ unsigned short Bs[2][BN * BK];   // 4 KB each  (24 KB total)

    const int bxh = blockIdx.x;
    const int tid = threadIdx.x;

    // XCD-chunked bijective bx remap (GX % 8 == 0 for all launches here)
    int bx = (bxh & 7) * (GX >> 3) + (bxh >> 3);

    int t, mtile, off, cnt;
    if (table != nullptr) {
        int v = table[bx];
        if (v < 0) return;
        t = v >> 16; mtile = v & 0xFFFF;
        off = offs[t]; cnt = offs[t + 1] - off;
    } else {
        t = 0; mtile = bx; off = 0; cnt = Btot;
    }
    const int n0 = blockIdx.y * BN;

    const int lane = tid & 63;
    const int wave = tid >> 6;
    const int wr = wave >> 1, wc = wave & 1;

    // ---- A staging geometry (R6-proven) ----
    const int rl   = lane >> 2;                 // 0..15 row within 16-row line
    const int csrc = ((lane & 3) ^ ((rl >> 1) & 3)) * 8;
    const unsigned short* Ab = A + ((size_t)(off + mtile * BM + rl)) * K + csrc;

    // ---- B staging geometry: n = lane, k-chunk c = wave ----
    const int bn = lane;                        // 0..63
    const int bc = wave;                        // 0..3 -> k = bc*8 .. +7
    const float* Wb = W + (size_t)t * K * N + n0 + bn;
    const int bslot = (bc ^ ((bn >> 1) & 3)) * 8;   // ushort offset of 16B slot
    float br[8];

    auto stage_a = [&](int buf, int k0) {
        #pragma unroll
        for (int jj = 0; jj < 2; ++jj) {
            int j = wave * 2 + jj;              // 0..7: A 16-row line
            GLOAD_LDS16(Ab + (size_t)(j * 16) * K + k0, &As[buf][j * 512]);
        }
    };
    auto load_b = [&](int k0) {
        const float* p = Wb + (size_t)(k0 + bc * 8) * N;
        #pragma unroll
        for (int j = 0; j < 8; ++j)
            br[j] = p[(size_t)j * N];
    };
    auto write_b = [&](int buf) {
        uint4 wv;
        wv.x = pack2_bf16(br[0], br[1]);
        wv.y = pack2_bf16(br[2], br[3]);
        wv.z = pack2_bf16(br[4], br[5]);
        wv.w = pack2_bf16(br[6], br[7]);
        *reinterpret_cast<uint4*>(&Bs[buf][bn * 32 + bslot]) = wv;
    };

    f32x4 acc[4][2];
    #pragma unroll
    for (int m = 0; m < 4; ++m)
        #pragma unroll
        for (int n = 0; n < 2; ++n)
            acc[m][n] = (f32x4){0.f, 0.f, 0.f, 0.f};

    auto compute = [&](int buf) {
        bf16x8 af[4], bfr[2];
        #pragma unroll
        for (int m = 0; m < 4; ++m) {
            int rf = wr * 64 + m * 16 + (lane & 15);
            af[m] = *reinterpret_cast<const bf16x8*>(
                &As[buf][rf * 32 + (((lane >> 4) ^ ((rf >> 1) & 3)) * 8)]);
        }
        #pragma unroll
        for (int n = 0; n < 2; ++n) {
            int nf = wc * 32 + n * 16 + (lane & 15);
            bfr[n] = *reinterpret_cast<const bf16x8*>(
                &Bs[buf][nf * 32 + (((lane >> 4) ^ ((nf >> 1) & 3)) * 8)]);
        }
        #pragma unroll
        for (int m = 0; m < 4; ++m)
            #pragma unroll
            for (int n = 0; n < 2; ++n)
                acc[m][n] = __builtin_amdgcn_mfma_f32_16x16x32_bf16(af[m], bfr[n], acc[m][n], 0, 0, 0);
    };

    // ---- prologue ----
    const int nsteps = K / BK;
    load_b(0);
    stage_a(0, 0);
    write_b(0);          // compiler waits br via vmcnt; gload_lds drains at barrier
    __syncthreads();

    int cur = 0;
    for (int s = 0; s < nsteps; ++s) {
        if (s + 1 < nsteps) {
            load_b((s + 1) * BK);            // B reg loads first (cvt waits only these)
            stage_a(cur ^ 1, (s + 1) * BK);  // A async -> LDS[next]
        }
        compute(cur);
        if (s + 1 < nsteps) write_b(cur ^ 1);
        __syncthreads();
        cur ^= 1;
    }

    // ---- epilogue ----
    const float* bt = bias + (size_t)t * N;
    #pragma unroll
    for (int n = 0; n < 2; ++n) {
        int col = n0 + wc * 32 + n * 16 + (lane & 15);
        float bv = bt[col];
        #pragma unroll
        for (int m = 0; m < 4; ++m) {
            int rbase = mtile * BM + wr * 64 + m * 16 + ((lane >> 4) << 2);
            #pragma unroll
            for (int j = 0; j < 4; ++j) {
                int local = rbase + j;
                if (local >= cnt) continue;
                float v = acc[m][n][j] + bv;
                if (MODE == 0) {
                    ((unsigned short*)dst)[(size_t)(off + local) * ldd + col] =
                        f32_to_bf16(fmaxf(v, 0.f));
                } else if (MODE == 1) {
                    ((float*)dst)[(size_t)(off + local) * ldd + col] = v;
                } else {
                    int grow = perm[off + local];
                    ((float*)dst)[(size_t)grow * ldd + col] = 1.f / (1.f + __expf(-v));
                }
            }
        }
    }
}

extern "C" void kernel_launch(void* const* d_in, const int* in_sizes, int n_in,
                              void* d_out, int out_size, void* d_ws, size_t ws_size,
                              hipStream_t stream) {
    const float* x      = (const float*)d_in[0];
    const int*   task   = (const int*)d_in[1];
    const float* eps    = (const float*)d_in[2];
    const float* enc_W1 = (const float*)d_in[3];
    const float* enc_b1 = (const float*)d_in[4];
    const float* enc_W2 = (const float*)d_in[5];
    const float* enc_b2 = (const float*)d_in[6];
    const float* enc_W3 = (const float*)d_in[7];
    const float* enc_b3 = (const float*)d_in[8];
    const float* enc_W4 = (const float*)d_in[9];
    const float* enc_b4 = (const float*)d_in[10];
    const float* ds_W1  = (const float*)d_in[11];
    const float* ds_b1  = (const float*)d_in[12];
    const float* ds_W2  = (const float*)d_in[13];
    const float* ds_b2  = (const float*)d_in[14];
    const float* hd_W1  = (const float*)d_in[15];
    const float* hd_b1  = (const float*)d_in[16];
    const float* hd_W2  = (const float*)d_in[17];
    const float* hd_b2  = (const float*)d_in[18];
    float* out = (float*)d_out;

    // ---- workspace layout (~52 MB) ----
    char* ws = (char*)d_ws;
    int* perm  = (int*)ws;
    int* offs  = (int*)(ws + 16384);
    int* table = (int*)(ws + 16384 + 256);
    char* p = ws + 32768;
    unsigned short* xp = (unsigned short*)p; p += (size_t)PADROWS * 1024 * 2;
    unsigned short* h1 = (unsigned short*)p; p += (size_t)PADROWS * 2048 * 2;
    unsigned short* h2 = (unsigned short*)p; p += (size_t)PADROWS * 2048 * 2;
    unsigned short* zb = (unsigned short*)p; p += (size_t)PADROWS * 256 * 2;
    float* scat = out;   // reuse d_out as 8 MB scat scratch; fully overwritten later

    setup_kernel<<<1, 1024, 0, stream>>>(task, perm, offs, table);
    permute_cast_kernel<<<B_ROWS, 256, 0, stream>>>(x, perm, xp);

    // encoder (grouped by task; GX=40, 40%8==0 for the XCD remap)
    gemm8_kernel<0><<<dim3(MAXTILES, 32), 256, 0, stream>>>(xp, enc_W1, enc_b1, h1, offs, table, nullptr, 1024, 2048, 2048, B_ROWS, MAXTILES);
    gemm8_kernel<0><<<dim3(MAXTILES, 32), 256, 0, stream>>>(h1, enc_W2, enc_b2, h2, offs, table, nullptr, 2048, 2048, 2048, B_ROWS, MAXTILES);
    gemm8_kernel<0><<<dim3(MAXTILES, 32), 256, 0, stream>>>(h2, enc_W3, enc_b3, h1, offs, table, nullptr, 2048, 2048, 2048, B_ROWS, MAXTILES);
    gemm8_kernel<1><<<dim3(MAXTILES, 8), 256, 0, stream>>>(h1, enc_W4, enc_b4, scat, offs, table, nullptr, 2048, 512, 512, B_ROWS, MAXTILES);

    vae_kernel<<<B_ROWS, 256, 0, stream>>>(scat, eps, perm, zb);

    // decoder shared layers (ungrouped: t=0, all rows; GX=32)
    gemm8_kernel<0><<<dim3(32, 32), 256, 0, stream>>>(zb, ds_W1, ds_b1, h2, nullptr, nullptr, nullptr, 256, 2048, 2048, B_ROWS, 32);
    gemm8_kernel<0><<<dim3(32, 32), 256, 0, stream>>>(h2, ds_W2, ds_b2, h1, nullptr, nullptr, nullptr, 2048, 2048, 2048, B_ROWS, 32);

    // heads (grouped)
    gemm8_kernel<0><<<dim3(MAXTILES, 32), 256, 0, stream>>>(h1, hd_W1, hd_b1, h2, offs, table, nullptr, 2048, 2048, 2048, B_ROWS, MAXTILES);
    gemm8_kernel<2><<<dim3(MAXTILES, 16), 256, 0, stream>>>(h2, hd_W2, hd_b2, out, offs, table, perm, 2048, 1024, 1024, B_ROWS, MAXTILES);
}